// Round 2
// baseline (75.879 us; speedup 1.0000x reference)
//
#include <hip/hip_runtime.h>
#include <hip/hip_bf16.h>

// FeaturesLinear: out[b] = sum_f W[x[b,f] + offsets[f]] + bias
// B=65536, F=26, W: (1040000,1) fp32 (L2/L3-resident), out: (65536,1) fp32.
//
// Lane-per-field layout: one 32-lane group per batch row (lanes 0..25 active).
//  - x reads coalesced: each group reads 26 consecutive ints (208 B/wave).
//  - W gather: one divergent 4B load per lane (vs 26 per thread before).
//  - 5-step shfl_xor reduce within the 32-lane group.
//  - 65536 rows * 32 lanes = 2M threads -> 8192 blocks -> 8 waves/SIMD (full
//    occupancy; was 1 wave/SIMD with thread-per-row), hiding gather latency.

#define NUM_FIELDS 26

__global__ __launch_bounds__(256) void FeaturesLinear_kernel(
    const int* __restrict__ x,        // (B, F) row-major
    const int* __restrict__ offsets,  // (F,)
    const float* __restrict__ W,      // (FEATURE_DIM, 1)
    const float* __restrict__ bias,   // (1,)
    float* __restrict__ out,          // (B, 1)
    int batch) {
  const int l = threadIdx.x & 31;                                  // lane in row-group
  const int row = (blockIdx.x * blockDim.x + threadIdx.x) >> 5;    // one 32-lane group per row
  if (row >= batch) return;

  // Clamp instead of predicate so the loads stay unconditional & in-bounds.
  const int lc = (l < NUM_FIELDS) ? l : (NUM_FIELDS - 1);
  const int idx = x[row * NUM_FIELDS + lc] + offsets[lc];
  float v = W[idx];
  if (l >= NUM_FIELDS) v = 0.f;

  // Reduce across the 32-lane group.
#pragma unroll
  for (int m = 16; m > 0; m >>= 1) v += __shfl_xor(v, m, 32);

  if (l == 0) out[row] = v + bias[0];
}

extern "C" void kernel_launch(void* const* d_in, const int* in_sizes, int n_in,
                              void* d_out, int out_size, void* d_ws, size_t ws_size,
                              hipStream_t stream) {
  const int* x = (const int*)d_in[0];
  const int* offsets = (const int*)d_in[1];
  const float* W = (const float*)d_in[2];
  const float* bias = (const float*)d_in[3];
  float* out = (float*)d_out;

  int batch = in_sizes[0] / NUM_FIELDS;  // 65536

  const int block = 256;                        // 8 row-groups per block
  const int rows_per_block = block / 32;
  dim3 grid((batch + rows_per_block - 1) / rows_per_block);
  FeaturesLinear_kernel<<<grid, dim3(block), 0, stream>>>(x, offsets, W, bias, out, batch);
}